// Round 4
// baseline (179.609 us; speedup 1.0000x reference)
//
#include <hip/hip_runtime.h>
#include <math.h>

#define T_TOK 8192
#define DDIM  4096
#define NEXP  64
#define TOPK  8
#define EG    16     // experts per wave (4 waves cover all 64)

// ---- K0: tiled transpose gate_weight [E][D] -> wt [D][E] ----
__global__ __launch_bounds__(256) void transpose_w(
    const float* __restrict__ gw, float* __restrict__ wt)
{
    __shared__ float tile[64][65];
    const int k0 = blockIdx.x * 64;
    const int t  = threadIdx.x;
    #pragma unroll
    for (int r = 0; r < 4; r++) {
        int f = r * 256 + t;          // 1024 float4 reads
        int e = f >> 4;
        int c = f & 15;
        float4 v = *reinterpret_cast<const float4*>(gw + (size_t)e * DDIM + k0 + c * 4);
        tile[c * 4 + 0][e] = v.x;
        tile[c * 4 + 1][e] = v.y;
        tile[c * 4 + 2][e] = v.z;
        tile[c * 4 + 3][e] = v.w;
    }
    __syncthreads();
    #pragma unroll
    for (int r = 0; r < 4; r++) {
        int f  = r * 256 + t;
        int k  = f >> 4;
        int ec = f & 15;
        float4 v = make_float4(tile[k][ec * 4 + 0], tile[k][ec * 4 + 1],
                               tile[k][ec * 4 + 2], tile[k][ec * 4 + 3]);
        *reinterpret_cast<float4*>(wt + (size_t)(k0 + k) * NEXP + ec * 4) = v;
    }
}

// ---- K1: logits partials. lane = token, W wave-uniform (SGPR), no LDS. ----
// Block: 4 waves, same 64 tokens, wave w -> experts [16w,16w+16).
// x rows shared via L1 across the 4 waves; HBM reads x once.
template<int KSLICE>
__global__ __launch_bounds__(256) void gemm_logits(
    const float* __restrict__ x, const float* __restrict__ wt,
    float* __restrict__ part)
{
    const int lane = threadIdx.x & 63;
    const int wave = threadIdx.x >> 6;
    const int e0   = __builtin_amdgcn_readfirstlane(wave * EG);
    const int tok  = blockIdx.x * 64 + lane;
    const int kb   = blockIdx.y * KSLICE;

    float acc[EG];
    #pragma unroll
    for (int j = 0; j < EG; j++) acc[j] = 0.f;

    const float4* __restrict__ xrow =
        reinterpret_cast<const float4*>(x + (size_t)tok * DDIM + kb);
    const float* __restrict__ wbase = wt + (size_t)kb * NEXP + e0;

    constexpr int NK4 = KSLICE / 4;
    #pragma unroll 4
    for (int k4 = 0; k4 < NK4; k4++) {
        float4 xv = xrow[k4];
        const float xk[4] = {xv.x, xv.y, xv.z, xv.w};
        const float* wp = wbase + (size_t)k4 * 4 * NEXP;
        #pragma unroll
        for (int kk = 0; kk < 4; kk++) {
            const float4* wr = reinterpret_cast<const float4*>(wp + kk * NEXP);
            #pragma unroll
            for (int q = 0; q < 4; q++) {
                float4 w = wr[q];                 // wave-uniform -> s_load
                acc[q * 4 + 0] = fmaf(xk[kk], w.x, acc[q * 4 + 0]);
                acc[q * 4 + 1] = fmaf(xk[kk], w.y, acc[q * 4 + 1]);
                acc[q * 4 + 2] = fmaf(xk[kk], w.z, acc[q * 4 + 2]);
                acc[q * 4 + 3] = fmaf(xk[kk], w.w, acc[q * 4 + 3]);
            }
        }
        if ((k4 & 63) == 63) __syncthreads();   // re-converge waves for L1 reuse
    }

    float* po = part + (size_t)blockIdx.y * T_TOK * NEXP
              + (size_t)tok * NEXP + e0;
    #pragma unroll
    for (int q = 0; q < 4; q++)
        *reinterpret_cast<float4*>(po + q * 4) =
            make_float4(acc[q * 4], acc[q * 4 + 1], acc[q * 4 + 2], acc[q * 4 + 3]);
}

// ---- K2: reduce partials, sigmoid, +bias, top-8, normalize ----
__global__ __launch_bounds__(256) void reduce_topk(
    const float* __restrict__ part, const float* __restrict__ bias,
    float* __restrict__ out, int S)
{
    const int wave  = threadIdx.x >> 6;
    const int lane  = threadIdx.x & 63;
    const int token = blockIdx.x * 4 + wave;
    if (token >= T_TOK) return;

    float logit = 0.f;
    for (int s = 0; s < S; s++)
        logit += part[(size_t)s * T_TOK * NEXP + (size_t)token * NEXP + lane];

    float score  = 1.f / (1.f + expf(-logit));
    float biased = score + bias[lane];

    float my_sc = 0.f;
    int   my_idx = 0;
    float ssum  = 0.f;

    #pragma unroll
    for (int j = 0; j < TOPK; j++) {
        float v = biased;
        int   i = lane;
        #pragma unroll
        for (int off = 32; off >= 1; off >>= 1) {
            float ov = __shfl_xor(v, off);
            int   oi = __shfl_xor(i, off);
            if (ov > v || (ov == v && oi < i)) { v = ov; i = oi; }
        }
        float s_sel = __shfl(score, i);
        ssum += s_sel;
        if (lane == j) { my_idx = i; my_sc = s_sel; }
        if (lane == i) biased = -INFINITY;
    }

    if (lane < TOPK) {
        out[(size_t)token * TOPK + lane] = (float)my_idx;                 // indices as f32
        out[(size_t)T_TOK * TOPK + (size_t)token * TOPK + lane]
            = my_sc / (ssum + 1e-20f);                                    // weights
    }
}

extern "C" void kernel_launch(void* const* d_in, const int* in_sizes, int n_in,
                              void* d_out, int out_size, void* d_ws, size_t ws_size,
                              hipStream_t stream) {
    (void)in_sizes; (void)n_in; (void)out_size;
    const float* x    = (const float*)d_in[0];
    const float* gw   = (const float*)d_in[1];
    const float* bias = (const float*)d_in[2];
    float* out  = (float*)d_out;
    float* wt   = (float*)d_ws;                     // [DDIM][NEXP], 1 MiB
    float* part = wt + (size_t)DDIM * NEXP;

    const size_t wt_bytes  = (size_t)DDIM * NEXP * sizeof(float);
    const size_t per_slice = (size_t)T_TOK * NEXP * sizeof(float);  // 2 MiB
    int S = 1;
    for (int cand : {8, 4, 2}) {
        if (wt_bytes + (size_t)cand * per_slice <= ws_size) { S = cand; break; }
    }

    transpose_w<<<DDIM / 64, 256, 0, stream>>>(gw, wt);

    dim3 g1(T_TOK / 64, S), b1(256);
    switch (S) {
        case 8: gemm_logits< 512><<<g1, b1, 0, stream>>>(x, wt, part); break;
        case 4: gemm_logits<1024><<<g1, b1, 0, stream>>>(x, wt, part); break;
        case 2: gemm_logits<2048><<<g1, b1, 0, stream>>>(x, wt, part); break;
        default: gemm_logits<4096><<<g1, b1, 0, stream>>>(x, wt, part); break;
    }

    dim3 g2((T_TOK + 3) / 4), b2(256);
    reduce_topk<<<g2, b2, 0, stream>>>(part, bias, out, S);
}

// Round 5
// 61.328 us; speedup vs baseline: 2.9287x; 2.9287x over previous
//
#include <hip/hip_runtime.h>
#include <math.h>

#define T_TOK 8192
#define DDIM  4096
#define NEXP  64
#define TOPK  8

typedef __attribute__((ext_vector_type(8))) _Float16 half8;
typedef __attribute__((ext_vector_type(4))) _Float16 half4v;
typedef __attribute__((ext_vector_type(4))) float f32x4;

#define RS 2048.0f

// ---- K0: pack gate_weight [E][D] f32 into MFMA B-fragment order, split f16.
// Layout: wpk[(kt*4 + n)*2 + p][lane][8]  (elems), p=0: h0, p=1: h1*2048.
// B frag (16x16x32): n-col = lane&15, k = kt*32 + (lane>>4)*8 + b.
__global__ __launch_bounds__(256) void pack_w(
    const float* __restrict__ gw, _Float16* __restrict__ wpk)
{
    const int g    = blockIdx.x * 256 + threadIdx.x;
    const int lane = g & 63;
    const int n    = (g >> 6) & 3;
    const int kt   = g >> 8;                     // 0..127
    const int e    = n * 16 + (lane & 15);
    const int k    = kt * 32 + (lane >> 4) * 8;

    const float* src = gw + (size_t)e * DDIM + k;
    float4 v0 = *reinterpret_cast<const float4*>(src);
    float4 v1 = *reinterpret_cast<const float4*>(src + 4);
    const float v[8] = {v0.x, v0.y, v0.z, v0.w, v1.x, v1.y, v1.z, v1.w};

    half8 h0, h1;
    #pragma unroll
    for (int j = 0; j < 8; j++) {
        _Float16 a = (_Float16)v[j];
        h0[j] = a;
        h1[j] = (_Float16)((v[j] - (float)a) * RS);
    }
    size_t base = ((size_t)(kt * 4 + n) * 2) * 512;     // 512 = 64 lanes * 8
    *reinterpret_cast<half8*>(wpk + base + lane * 8)       = h0;
    *reinterpret_cast<half8*>(wpk + base + 512 + lane * 8) = h1;
}

// ---- K1: fused logits GEMM (f16-split MFMA) + sigmoid + top-8 ----
// 16 tokens/block, grid 512 (2 blocks/CU). 4 waves = 4 N-subtiles (16 experts).
// A: global f32 -> reg -> (h0, h1*2048) -> double-buffered LDS.
// B: pre-packed frags, direct global b128 (L2-resident).
__global__ __launch_bounds__(256) void gemm_topk(
    const float* __restrict__ x, const _Float16* __restrict__ wpk,
    const float* __restrict__ bias, float* __restrict__ out)
{
    __shared__ _Float16 A_lds[2][2][16][136];   // [buf][plane][tok][k], stride 136 -> 2-way banks (free)
    __shared__ float lg[16][66];

    const int tid  = threadIdx.x;
    const int lane = tid & 63;
    const int wv   = tid >> 6;                  // wave = N-subtile
    const int tok0 = blockIdx.x * 16;

    const int s_tok = tid >> 5;                 // 0..7 (staging row)
    const int s_c   = tid & 31;                 // float4 column

    const float* xr0 = x + (size_t)(tok0 + s_tok)     * DDIM + s_c * 4;
    const float* xr1 = x + (size_t)(tok0 + s_tok + 8) * DDIM + s_c * 4;

    f32x4 accH = {0.f, 0.f, 0.f, 0.f};
    f32x4 accM = accH, accL = accH;

    float4 pf0 = *reinterpret_cast<const float4*>(xr0);
    float4 pf1 = *reinterpret_cast<const float4*>(xr1);

    const int am = lane & 15;                   // token row in frag
    const int ag = lane >> 4;                   // k-group

    for (int io = 0; io < 32; ++io) {
        // B frags for this iter (8 x b128, L2-resident) — issue early
        half8 B0[4], B1[4];
        #pragma unroll
        for (int ks = 0; ks < 4; ks++) {
            const _Float16* bp = wpk + ((size_t)((io * 4 + ks) * 4 + wv) * 2) * 512 + lane * 8;
            B0[ks] = *reinterpret_cast<const half8*>(bp);
            B1[ks] = *reinterpret_cast<const half8*>(bp + 512);
        }
        // prefetch next A tile (hides HBM latency under stage+barrier+MFMA)
        float4 nf0 = pf0, nf1 = pf1;
        if (io < 31) {
            nf0 = *reinterpret_cast<const float4*>(xr0 + (io + 1) * 128);
            nf1 = *reinterpret_cast<const float4*>(xr1 + (io + 1) * 128);
        }
        // convert + stage current A into buf b
        const int b = io & 1;
        {
            half4v p = { (_Float16)pf0.x, (_Float16)pf0.y, (_Float16)pf0.z, (_Float16)pf0.w };
            half4v r = { (_Float16)((pf0.x - (float)p[0]) * RS),
                         (_Float16)((pf0.y - (float)p[1]) * RS),
                         (_Float16)((pf0.z - (float)p[2]) * RS),
                         (_Float16)((pf0.w - (float)p[3]) * RS) };
            *reinterpret_cast<half4v*>(&A_lds[b][0][s_tok][s_c * 4]) = p;
            *reinterpret_cast<half4v*>(&A_lds[b][1][s_tok][s_c * 4]) = r;
        }
        {
            half4v p = { (_Float16)pf1.x, (_Float16)pf1.y, (_Float16)pf1.z, (_Float16)pf1.w };
            half4v r = { (_Float16)((pf1.x - (float)p[0]) * RS),
                         (_Float16)((pf1.y - (float)p[1]) * RS),
                         (_Float16)((pf1.z - (float)p[2]) * RS),
                         (_Float16)((pf1.w - (float)p[3]) * RS) };
            *reinterpret_cast<half4v*>(&A_lds[b][0][s_tok + 8][s_c * 4]) = p;
            *reinterpret_cast<half4v*>(&A_lds[b][1][s_tok + 8][s_c * 4]) = r;
        }
        __syncthreads();   // one barrier/iter: writes(buf b) -> reads(buf b); next iter writes b^1

        #pragma unroll
        for (int ks = 0; ks < 4; ks++) {
            half8 a0 = *reinterpret_cast<const half8*>(&A_lds[b][0][am][ks * 32 + ag * 8]);
            half8 a1 = *reinterpret_cast<const half8*>(&A_lds[b][1][am][ks * 32 + ag * 8]);
            accH = __builtin_amdgcn_mfma_f32_16x16x32_f16(a0, B0[ks], accH, 0, 0, 0);
            accM = __builtin_amdgcn_mfma_f32_16x16x32_f16(a0, B1[ks], accM, 0, 0, 0);
            accM = __builtin_amdgcn_mfma_f32_16x16x32_f16(a1, B0[ks], accM, 0, 0, 0);
            accL = __builtin_amdgcn_mfma_f32_16x16x32_f16(a1, B1[ks], accL, 0, 0, 0);
        }
        pf0 = nf0; pf1 = nf1;
    }

    // combine scale-separated accumulators -> logits in LDS
    // C/D layout (m89-verified): col = lane&15 (expert), row = (lane>>4)*4 + r (token)
    const float i1 = 1.0f / RS, i2 = 1.0f / (RS * RS);
    #pragma unroll
    for (int r = 0; r < 4; r++) {
        float vv = accH[r] + accM[r] * i1 + accL[r] * i2;
        lg[ag * 4 + r][wv * 16 + am] = vv;
    }
    __syncthreads();

    // fused top-8: wave wv handles tokens wv*4 .. wv*4+3, lane = expert
    const float bsv = bias[lane];
    #pragma unroll
    for (int ti = 0; ti < 4; ti++) {
        const int tk = wv * 4 + ti;
        float logit  = lg[tk][lane];
        float score  = 1.f / (1.f + expf(-logit));
        float biased = score + bsv;
        float my_sc = 0.f; int my_idx = 0; float ssum = 0.f;
        #pragma unroll
        for (int j = 0; j < TOPK; j++) {
            float vb = biased; int ib = lane;
            #pragma unroll
            for (int off = 32; off >= 1; off >>= 1) {
                float ov = __shfl_xor(vb, off);
                int   oi = __shfl_xor(ib, off);
                if (ov > vb || (ov == vb && oi < ib)) { vb = ov; ib = oi; }
            }
            float s_sel = __shfl(score, ib);
            ssum += s_sel;
            if (lane == j) { my_idx = ib; my_sc = s_sel; }
            if (lane == ib) biased = -INFINITY;
        }
        if (lane < TOPK) {
            out[(size_t)(tok0 + tk) * TOPK + lane] = (float)my_idx;           // indices as f32
            out[(size_t)T_TOK * TOPK + (size_t)(tok0 + tk) * TOPK + lane]
                = my_sc / (ssum + 1e-20f);                                    // weights
        }
    }
}

extern "C" void kernel_launch(void* const* d_in, const int* in_sizes, int n_in,
                              void* d_out, int out_size, void* d_ws, size_t ws_size,
                              hipStream_t stream) {
    (void)in_sizes; (void)n_in; (void)out_size; (void)ws_size;
    const float* x    = (const float*)d_in[0];
    const float* gw   = (const float*)d_in[1];
    const float* bias = (const float*)d_in[2];
    float* out = (float*)d_out;
    _Float16* wpk = (_Float16*)d_ws;            // 1 MiB packed W frags

    pack_w<<<128, 256, 0, stream>>>(gw, wpk);
    gemm_topk<<<T_TOK / 16, 256, 0, stream>>>(x, wpk, bias, out);
}

// Round 6
// 60.063 us; speedup vs baseline: 2.9903x; 1.0211x over previous
//
#include <hip/hip_runtime.h>
#include <math.h>

#define T_TOK 8192
#define DDIM  4096
#define NEXP  64
#define TOPK  8

typedef __attribute__((ext_vector_type(8))) _Float16 half8;
typedef __attribute__((ext_vector_type(4))) float f32x4;

#define RS 2048.0f

// ---- K0: pack gate_weight [E][D] f32 into MFMA B-fragment order, split f16.
// wpk[(kt*4 + n)*2 + p][lane][8], p=0: h0, p=1: (w-h0)*2048.
// B frag (16x16x32): expert col = n*16 + (lane&15), k = kt*32 + (lane>>4)*8 + j.
__global__ __launch_bounds__(256) void pack_w(
    const float* __restrict__ gw, _Float16* __restrict__ wpk)
{
    const int g    = blockIdx.x * 256 + threadIdx.x;
    const int lane = g & 63;
    const int n    = (g >> 6) & 3;
    const int kt   = g >> 8;                     // 0..127
    const int e    = n * 16 + (lane & 15);
    const int k    = kt * 32 + (lane >> 4) * 8;

    const float* src = gw + (size_t)e * DDIM + k;
    float4 v0 = *reinterpret_cast<const float4*>(src);
    float4 v1 = *reinterpret_cast<const float4*>(src + 4);
    const float v[8] = {v0.x, v0.y, v0.z, v0.w, v1.x, v1.y, v1.z, v1.w};

    half8 h0, h1;
    #pragma unroll
    for (int j = 0; j < 8; j++) {
        _Float16 a = (_Float16)v[j];
        h0[j] = a;
        h1[j] = (_Float16)((v[j] - (float)a) * RS);
    }
    size_t base = ((size_t)(kt * 4 + n) * 2) * 512;
    *reinterpret_cast<half8*>(wpk + base + lane * 8)       = h0;
    *reinterpret_cast<half8*>(wpk + base + 512 + lane * 8) = h1;
}

// ---- K1: barrier-free, LDS-free logits partials via f16-split MFMA ----
// One wave = 16 tokens x 64 experts x (DDIM/S) k.  Lane(am,ag) loads its own
// A-fragment straight from global: 32 B/lane, wave covers 16 rows x 128 B
// (full lines).  Waves fully independent -> pure TLP latency hiding.
template<int S>
__global__ __launch_bounds__(256, 4) void gemm_part(
    const float* __restrict__ x, const _Float16* __restrict__ wpk,
    float* __restrict__ part)
{
    constexpr int STEPS = 128 / S;               // 32-k steps per slice
    const int lane = threadIdx.x & 63;
    const int wid  = (blockIdx.x * 256 + threadIdx.x) >> 6;
    const int tile = wid & 511;                  // token tile
    const int slc  = wid >> 9;                   // k-slice
    const int tok0 = tile * 16;
    const int am   = lane & 15;
    const int ag   = lane >> 4;

    const float* xr = x + (size_t)(tok0 + am) * DDIM + slc * (DDIM / S) + ag * 8;

    f32x4 acc[4][3];                             // [n-frag][plane H,M,L]
    #pragma unroll
    for (int n = 0; n < 4; n++)
        #pragma unroll
        for (int p = 0; p < 3; p++) acc[n][p] = (f32x4){0.f, 0.f, 0.f, 0.f};

    #pragma unroll 4
    for (int st = 0; st < STEPS; st++) {
        float4 v0 = *reinterpret_cast<const float4*>(xr + st * 32);
        float4 v1 = *reinterpret_cast<const float4*>(xr + st * 32 + 4);
        const float v[8] = {v0.x, v0.y, v0.z, v0.w, v1.x, v1.y, v1.z, v1.w};
        half8 a0, a1;
        #pragma unroll
        for (int j = 0; j < 8; j++) {
            _Float16 h = (_Float16)v[j];
            a0[j] = h;
            a1[j] = (_Float16)((v[j] - (float)h) * RS);
        }
        const int kt = slc * STEPS + st;
        const _Float16* bp = wpk + ((size_t)kt * 8) * 512 + lane * 8;
        #pragma unroll
        for (int n = 0; n < 4; n++) {
            half8 B0 = *reinterpret_cast<const half8*>(bp + n * 1024);
            half8 B1 = *reinterpret_cast<const half8*>(bp + n * 1024 + 512);
            acc[n][0] = __builtin_amdgcn_mfma_f32_16x16x32_f16(a0, B0, acc[n][0], 0, 0, 0);
            acc[n][1] = __builtin_amdgcn_mfma_f32_16x16x32_f16(a0, B1, acc[n][1], 0, 0, 0);
            acc[n][1] = __builtin_amdgcn_mfma_f32_16x16x32_f16(a1, B0, acc[n][1], 0, 0, 0);
            acc[n][2] = __builtin_amdgcn_mfma_f32_16x16x32_f16(a1, B1, acc[n][2], 0, 0, 0);
        }
    }

    // combine planes; C/D layout (m89): col=lane&15 (expert), row=(lane>>4)*4+r
    const float i1 = 1.0f / RS, i2 = 1.0f / (RS * RS);
    float* po = part + (size_t)slc * T_TOK * NEXP + (size_t)tok0 * NEXP;
    #pragma unroll
    for (int n = 0; n < 4; n++) {
        #pragma unroll
        for (int r = 0; r < 4; r++) {
            float vv = acc[n][0][r] + acc[n][1][r] * i1 + acc[n][2][r] * i2;
            po[(size_t)(ag * 4 + r) * NEXP + n * 16 + am] = vv;
        }
    }
}

// ---- K2: reduce partials, sigmoid, +bias, top-8, normalize ----
__global__ __launch_bounds__(256) void reduce_topk(
    const float* __restrict__ part, const float* __restrict__ bias,
    float* __restrict__ out, int S)
{
    const int wave  = threadIdx.x >> 6;
    const int lane  = threadIdx.x & 63;
    const int token = blockIdx.x * 4 + wave;
    if (token >= T_TOK) return;

    float logit = 0.f;
    for (int s = 0; s < S; s++)
        logit += part[(size_t)s * T_TOK * NEXP + (size_t)token * NEXP + lane];

    float score  = 1.f / (1.f + expf(-logit));
    float biased = score + bias[lane];

    float my_sc = 0.f;
    int   my_idx = 0;
    float ssum  = 0.f;

    #pragma unroll
    for (int j = 0; j < TOPK; j++) {
        float v = biased;
        int   i = lane;
        #pragma unroll
        for (int off = 32; off >= 1; off >>= 1) {
            float ov = __shfl_xor(v, off);
            int   oi = __shfl_xor(i, off);
            if (ov > v || (ov == v && oi < i)) { v = ov; i = oi; }
        }
        float s_sel = __shfl(score, i);
        ssum += s_sel;
        if (lane == j) { my_idx = i; my_sc = s_sel; }
        if (lane == i) biased = -INFINITY;
    }

    if (lane < TOPK) {
        out[(size_t)token * TOPK + lane] = (float)my_idx;                 // indices as f32
        out[(size_t)T_TOK * TOPK + (size_t)token * TOPK + lane]
            = my_sc / (ssum + 1e-20f);                                    // weights
    }
}

extern "C" void kernel_launch(void* const* d_in, const int* in_sizes, int n_in,
                              void* d_out, int out_size, void* d_ws, size_t ws_size,
                              hipStream_t stream) {
    (void)in_sizes; (void)n_in; (void)out_size;
    const float* x    = (const float*)d_in[0];
    const float* gw   = (const float*)d_in[1];
    const float* bias = (const float*)d_in[2];
    float* out = (float*)d_out;
    _Float16* wpk = (_Float16*)d_ws;                         // 1 MiB packed W frags
    float* part = (float*)(wpk + (size_t)DDIM * NEXP * 2);   // S x [T][E] f32

    const size_t wpk_bytes = (size_t)DDIM * NEXP * 2 * sizeof(_Float16);
    const size_t per_slice = (size_t)T_TOK * NEXP * sizeof(float);       // 2 MiB
    int S = 1;
    for (int cand : {8, 4, 2}) {
        if (wpk_bytes + (size_t)cand * per_slice <= ws_size) { S = cand; break; }
    }

    pack_w<<<128, 256, 0, stream>>>(gw, wpk);

    dim3 b1(256);
    switch (S) {
        case 8: gemm_part<8><<<dim3(128 * 8), b1, 0, stream>>>(x, wpk, part); break;
        case 4: gemm_part<4><<<dim3(128 * 4), b1, 0, stream>>>(x, wpk, part); break;
        case 2: gemm_part<2><<<dim3(128 * 2), b1, 0, stream>>>(x, wpk, part); break;
        default: gemm_part<1><<<dim3(128), b1, 0, stream>>>(x, wpk, part); break;
    }

    reduce_topk<<<dim3(T_TOK / 4), 256, 0, stream>>>(part, bias, out, S);
}

// Round 7
// 53.920 us; speedup vs baseline: 3.3310x; 1.1139x over previous
//
#include <hip/hip_runtime.h>
#include <math.h>

#define T_TOK 8192
#define DDIM  4096
#define NEXP  64
#define TOPK  8

typedef __attribute__((ext_vector_type(8))) _Float16 half8;
typedef __attribute__((ext_vector_type(4))) float f32x4;

#define RS 2048.0f

// ---- K0: pack gate_weight [E][D] f32 into MFMA B-fragment order, split f16.
// wpk[(kt*4 + n)*2 + p][lane][8], p=0: h0, p=1: (w-h0)*2048.
// B frag (16x16x32): expert col = n*16 + (lane&15), k = kt*32 + (lane>>4)*8 + j.
__global__ __launch_bounds__(256) void pack_w(
    const float* __restrict__ gw, _Float16* __restrict__ wpk)
{
    const int g    = blockIdx.x * 256 + threadIdx.x;
    const int lane = g & 63;
    const int n    = (g >> 6) & 3;
    const int kt   = g >> 8;                     // 0..127
    const int e    = n * 16 + (lane & 15);
    const int k    = kt * 32 + (lane >> 4) * 8;

    const float* src = gw + (size_t)e * DDIM + k;
    float4 v0 = *reinterpret_cast<const float4*>(src);
    float4 v1 = *reinterpret_cast<const float4*>(src + 4);
    const float v[8] = {v0.x, v0.y, v0.z, v0.w, v1.x, v1.y, v1.z, v1.w};

    half8 h0, h1;
    #pragma unroll
    for (int j = 0; j < 8; j++) {
        _Float16 a = (_Float16)v[j];
        h0[j] = a;
        h1[j] = (_Float16)((v[j] - (float)a) * RS);
    }
    size_t base = ((size_t)(kt * 4 + n) * 2) * 512;
    *reinterpret_cast<half8*>(wpk + base + lane * 8)       = h0;
    *reinterpret_cast<half8*>(wpk + base + 512 + lane * 8) = h1;
}

// ---- K1: barrier-free f16-split MFMA partials, 2 M-tiles per wave ----
// Wave = 32 tokens x 64 experts x (DDIM/S) k.  B stream shared by both
// M-tiles (halves B traffic).  Explicit register pipeline: A 2 steps ahead
// (depth-3), B 1 step ahead (depth-2).  No LDS, no barriers.
template<int S>
__global__ __launch_bounds__(256, 2) void gemm_part(
    const float* __restrict__ x, const _Float16* __restrict__ wpk,
    float* __restrict__ part)
{
    constexpr int STEPS = 128 / S;               // 32-k steps per slice
    const int lane = threadIdx.x & 63;
    const int wv   = threadIdx.x >> 6;
    const int slc  = blockIdx.x >> 6;            // 64 blocks per slice
    const int pair = ((blockIdx.x & 63) << 2) | wv;   // 0..255
    const int tok0 = pair * 32;
    const int am   = lane & 15;
    const int ag   = lane >> 4;

    const float* xr0 = x + (size_t)(tok0 + am) * DDIM + slc * (DDIM / S) + ag * 8;
    const float* xr1 = xr0 + (size_t)16 * DDIM;
    const _Float16* bbase = wpk + (size_t)slc * STEPS * 8 * 512 + lane * 8;

    f32x4 aH[2][4], aM[2][4];
    #pragma unroll
    for (int t = 0; t < 2; t++)
        #pragma unroll
        for (int n = 0; n < 4; n++) {
            aH[t][n] = (f32x4){0.f, 0.f, 0.f, 0.f};
            aM[t][n] = (f32x4){0.f, 0.f, 0.f, 0.f};
        }

    float4 av[3][4];     // A pipeline, depth 3 (2-step lookahead)
    half8  bf[2][8];     // B pipeline, depth 2

    // prologue: A for steps 0,1; B for step 0
    #pragma unroll
    for (int st = 0; st < 2; st++) {
        av[st][0] = *reinterpret_cast<const float4*>(xr0 + st * 32);
        av[st][1] = *reinterpret_cast<const float4*>(xr0 + st * 32 + 4);
        av[st][2] = *reinterpret_cast<const float4*>(xr1 + st * 32);
        av[st][3] = *reinterpret_cast<const float4*>(xr1 + st * 32 + 4);
    }
    #pragma unroll
    for (int n = 0; n < 4; n++) {
        bf[0][2 * n]     = *reinterpret_cast<const half8*>(bbase + n * 1024);
        bf[0][2 * n + 1] = *reinterpret_cast<const half8*>(bbase + n * 1024 + 512);
    }

    #pragma unroll
    for (int st = 0; st < STEPS; st++) {
        const int cur  = st & 1;
        const int nxt  = cur ^ 1;
        const int acur = st % 3;

        if (st + 2 < STEPS) {                     // A prefetch, 2 ahead
            const int ap = (st + 2) % 3;
            av[ap][0] = *reinterpret_cast<const float4*>(xr0 + (st + 2) * 32);
            av[ap][1] = *reinterpret_cast<const float4*>(xr0 + (st + 2) * 32 + 4);
            av[ap][2] = *reinterpret_cast<const float4*>(xr1 + (st + 2) * 32);
            av[ap][3] = *reinterpret_cast<const float4*>(xr1 + (st + 2) * 32 + 4);
        }
        if (st + 1 < STEPS) {                     // B prefetch, 1 ahead
            const _Float16* bp = bbase + (size_t)(st + 1) * 8 * 512;
            #pragma unroll
            for (int n = 0; n < 4; n++) {
                bf[nxt][2 * n]     = *reinterpret_cast<const half8*>(bp + n * 1024);
                bf[nxt][2 * n + 1] = *reinterpret_cast<const half8*>(bp + n * 1024 + 512);
            }
        }

        half8 a0[2], a1[2];
        #pragma unroll
        for (int t = 0; t < 2; t++) {
            const float* vv = reinterpret_cast<const float*>(&av[acur][2 * t]);
            #pragma unroll
            for (int j = 0; j < 8; j++) {
                float v = vv[j];
                _Float16 h = (_Float16)v;
                a0[t][j] = h;
                a1[t][j] = (_Float16)((v - (float)h) * RS);
            }
        }
        #pragma unroll
        for (int t = 0; t < 2; t++)
            #pragma unroll
            for (int n = 0; n < 4; n++) {
                aH[t][n] = __builtin_amdgcn_mfma_f32_16x16x32_f16(a0[t], bf[cur][2 * n],     aH[t][n], 0, 0, 0);
                aM[t][n] = __builtin_amdgcn_mfma_f32_16x16x32_f16(a0[t], bf[cur][2 * n + 1], aM[t][n], 0, 0, 0);
                aM[t][n] = __builtin_amdgcn_mfma_f32_16x16x32_f16(a1[t], bf[cur][2 * n],     aM[t][n], 0, 0, 0);
            }
    }

    // combine planes; C/D layout (m89): col=lane&15 (expert), row=(lane>>4)*4+r
    const float i1 = 1.0f / RS;
    float* po = part + (size_t)slc * T_TOK * NEXP + (size_t)tok0 * NEXP;
    #pragma unroll
    for (int t = 0; t < 2; t++)
        #pragma unroll
        for (int n = 0; n < 4; n++)
            #pragma unroll
            for (int r = 0; r < 4; r++) {
                float vv = aH[t][n][r] + aM[t][n][r] * i1;
                po[(size_t)(t * 16 + ag * 4 + r) * NEXP + n * 16 + am] = vv;
            }
}

// ---- K2: reduce partials, sigmoid, +bias, top-8, normalize ----
// Block swizzle: reader XCD (blockIdx%8) == writer XCD ((token/128)%8).
__global__ __launch_bounds__(256) void reduce_topk(
    const float* __restrict__ part, const float* __restrict__ bias,
    float* __restrict__ out, int S)
{
    const int wave = threadIdx.x >> 6;
    const int lane = threadIdx.x & 63;
    const int j    = blockIdx.x;                 // 0..2047
    const int g    = j & 7;
    const int q    = j >> 3;
    const int token = g * 128 + (q & 31) * 4 + (q >> 5) * 1024 + wave;
    if (token >= T_TOK) return;

    float logit = 0.f;
    for (int s = 0; s < S; s++)
        logit += part[(size_t)s * T_TOK * NEXP + (size_t)token * NEXP + lane];

    float score  = 1.f / (1.f + expf(-logit));
    float biased = score + bias[lane];

    float my_sc = 0.f;
    int   my_idx = 0;
    float ssum  = 0.f;

    #pragma unroll
    for (int jj = 0; jj < TOPK; jj++) {
        float v = biased;
        int   i = lane;
        #pragma unroll
        for (int off = 32; off >= 1; off >>= 1) {
            float ov = __shfl_xor(v, off);
            int   oi = __shfl_xor(i, off);
            if (ov > v || (ov == v && oi < i)) { v = ov; i = oi; }
        }
        float s_sel = __shfl(score, i);
        ssum += s_sel;
        if (lane == jj) { my_idx = i; my_sc = s_sel; }
        if (lane == i) biased = -INFINITY;
    }

    if (lane < TOPK) {
        out[(size_t)token * TOPK + lane] = (float)my_idx;                 // indices as f32
        out[(size_t)T_TOK * TOPK + (size_t)token * TOPK + lane]
            = my_sc / (ssum + 1e-20f);                                    // weights
    }
}

extern "C" void kernel_launch(void* const* d_in, const int* in_sizes, int n_in,
                              void* d_out, int out_size, void* d_ws, size_t ws_size,
                              hipStream_t stream) {
    (void)in_sizes; (void)n_in; (void)out_size;
    const float* x    = (const float*)d_in[0];
    const float* gw   = (const float*)d_in[1];
    const float* bias = (const float*)d_in[2];
    float* out = (float*)d_out;
    _Float16* wpk = (_Float16*)d_ws;                         // 1 MiB packed W frags
    float* part = (float*)(wpk + (size_t)DDIM * NEXP * 2);   // S x [T][E] f32

    const size_t wpk_bytes = (size_t)DDIM * NEXP * 2 * sizeof(_Float16);
    const size_t per_slice = (size_t)T_TOK * NEXP * sizeof(float);       // 2 MiB
    int S = 1;
    for (int cand : {8, 4, 2}) {
        if (wpk_bytes + (size_t)cand * per_slice <= ws_size) { S = cand; break; }
    }

    pack_w<<<128, 256, 0, stream>>>(gw, wpk);

    dim3 b1(256);
    switch (S) {
        case 8: gemm_part<8><<<dim3(64 * 8), b1, 0, stream>>>(x, wpk, part); break;
        case 4: gemm_part<4><<<dim3(64 * 4), b1, 0, stream>>>(x, wpk, part); break;
        case 2: gemm_part<2><<<dim3(64 * 2), b1, 0, stream>>>(x, wpk, part); break;
        default: gemm_part<1><<<dim3(64), b1, 0, stream>>>(x, wpk, part); break;
    }

    reduce_topk<<<dim3(T_TOK / 4), 256, 0, stream>>>(part, bias, out, S);
}